// Round 13
// baseline (638.220 us; speedup 1.0000x reference)
//
#include <hip/hip_runtime.h>
#include <math.h>

#define TT 512
#define BB 512
#define FF 14
#define H1 32
#define H2 64

typedef _Float16 h2v __attribute__((ext_vector_type(2)));

__device__ __forceinline__ float rcpf_(float x) { return __builtin_amdgcn_rcpf(x); }
__device__ __forceinline__ float sigmoidf_(float x) {
    return rcpf_(1.0f + __expf(-x));
}
__device__ __forceinline__ float tanhf_(float x) {
    float e = __expf(-2.0f * fabsf(x));
    float t = (1.0f - e) * rcpf_(1.0f + e);
    return copysignf(t, x);
}
__device__ __forceinline__ float fdot2_(h2v a, h2v b, float c) {
#if __has_builtin(__builtin_amdgcn_fdot2)
    return __builtin_amdgcn_fdot2(a, b, c, false);
#else
    return fmaf((float)a.x, (float)b.x, fmaf((float)a.y, (float)b.y, c));
#endif
}
__device__ __forceinline__ h2v bc_(unsigned u) { return __builtin_bit_cast(h2v, u); }
__device__ __forceinline__ h2v pk_(float lo, float hi) {
    h2v r; r.x = (_Float16)lo; r.y = (_Float16)hi; return r;
}
template <int CTRL>
__device__ __forceinline__ float dpp_mov(float v) {
    return __int_as_float(__builtin_amdgcn_update_dpp(
        0, __float_as_int(v), CTRL, 0xF, 0xF, true));
}

// TWO rows per block, 256 blocks = 1 block/CU, 512 threads (8 BALANCED waves).
// R12 analysis: VALU-issue-bound per SIMD (13 unbalanced waves; heaviest SIMD
// sets the barrier interval). Here every lane carries: (a) its R12 layer-2
// gate-half role for BOTH rows (w2 = 24 dwords in regs, proven resident), and
// (b) exactly one layer-1 (gate,half,row) slot — 512 slots = 512 lanes,
// 12 dot2 each, weights streamed from LDS (12 KB) to avoid the register
// allocator fights of rounds 1-6. Stager wave removed (x staging on 28 owner
// lanes; load latency spans the barrier). One barrier/step, R12 parities.
__global__ __launch_bounds__(512) void lstm3_kernel(
    const float* __restrict__ x,
    const float* __restrict__ Wih1, const float* __restrict__ Whh1,
    const float* __restrict__ bih1, const float* __restrict__ bhh1,
    const float* __restrict__ Wih2, const float* __restrict__ Whh2,
    const float* __restrict__ bih2, const float* __restrict__ bhh2,
    const float* __restrict__ Wfc1, const float* __restrict__ bfc1,
    const float* __restrict__ Wfc2, const float* __restrict__ bfc2,
    const float* __restrict__ Wfc,  const float* __restrict__ bfc,
    float* __restrict__ out)
{
    const int row0 = 2 * blockIdx.x;
    const int l    = threadIdx.x;

    // L1 weights in LDS: row (32*ty+u1)*2+hf, 12 dwords (48 B, 16B-aligned)
    __shared__ __align__(16) unsigned ws1[256][12];
    // Packed f16-pair state per [parity][row]:
    // s2cat: 48 dw = [h1 (16 dw) | h2 (32 dw)] ; s1cat: 24 dw = [x|pad|h1]
    __shared__ __align__(16) unsigned s2cat[2][2][48];
    __shared__ __align__(16) unsigned s1cat[2][2][24];
    __shared__ float mlp1[2][8];
    __shared__ float mlp2[2][8];

    // ---- L2 role (identical to R12): unit u2, type ty2, half hf2 ----
    const int u2  = l >> 3;          // 0..63
    const int hf2 = l & 1;
    // ---- L1 role: unit u1, row rw1, type, half — one slot per lane ----
    const int u1  = l >> 4;          // 0..31
    const int rw1 = (l >> 3) & 1;    // row bit
    const int hf1 = l & 1;
    const int r1  = 32 * ((l >> 1) & 3) + u1;   // layer-1 gate row (i,f,g,o blocks)

    // ---- layer-2 weights: 24 packed f16 pairs in VGPRs (both rows reuse) ----
    h2v  w2[24];
    float b2r = 0.0f;
    {
        const int ty2 = (l >> 1) & 3;
        const int r2  = 64 * ty2 + u2;
        if (hf2 == 0) {
            const float4* p = (const float4*)(Wih2 + r2 * H1);
            #pragma unroll
            for (int k = 0; k < 8; ++k) {
                float4 v = p[k];
                w2[2 * k] = pk_(v.x, v.y); w2[2 * k + 1] = pk_(v.z, v.w);
            }
            const float4* q = (const float4*)(Whh2 + r2 * H2);
            #pragma unroll
            for (int k = 0; k < 4; ++k) {
                float4 v = q[k];
                w2[16 + 2 * k] = pk_(v.x, v.y); w2[16 + 2 * k + 1] = pk_(v.z, v.w);
            }
            b2r = bih2[r2] + bhh2[r2];
        } else {
            const float4* q = (const float4*)(Whh2 + r2 * H2);
            #pragma unroll
            for (int k = 0; k < 12; ++k) {
                float4 v = q[4 + k];
                w2[2 * k] = pk_(v.x, v.y); w2[2 * k + 1] = pk_(v.z, v.w);
            }
        }
    }

    // ---- layer-1 bias (one float; only hf1==0 lanes carry it) ----
    const float b1r = (hf1 == 0) ? (bih1[r1] + bhh1[r1]) : 0.0f;

    // ---- fill ws1 (threads 0..255, R12's builder written to LDS) ----
    if (l < 256) {
        const int uf = l >> 3, tyf = (l >> 1) & 3, hff = l & 1;
        const int rf = 32 * tyf + uf;
        h2v wt[12];
        if (hff == 0) {
            float tmp[16];
            #pragma unroll
            for (int k = 0; k < FF; ++k) tmp[k] = Wih1[rf * FF + k];
            tmp[14] = 0.0f; tmp[15] = 0.0f;
            #pragma unroll
            for (int j = 0; j < 8; ++j) wt[j] = pk_(tmp[2 * j], tmp[2 * j + 1]);
            const float4* q = (const float4*)(Whh1 + rf * H1);
            float4 v = q[0];
            wt[8] = pk_(v.x, v.y); wt[9] = pk_(v.z, v.w);
            v = q[1];
            wt[10] = pk_(v.x, v.y); wt[11] = pk_(v.z, v.w);
        } else {
            const float4* q = (const float4*)(Whh1 + rf * H1);
            #pragma unroll
            for (int k = 0; k < 6; ++k) {
                float4 v = q[2 + k];
                wt[2 * k] = pk_(v.x, v.y); wt[2 * k + 1] = pk_(v.z, v.w);
            }
        }
        #pragma unroll
        for (int j = 0; j < 12; ++j)
            ws1[rf * 2 + hff][j] = __builtin_bit_cast(unsigned, wt[j]);
    }

    float c1r  = 0.0f;   // layer-1 cell state for (u1, rw1): owner lanes
    float xreg = 0.0f;   // x prefetch

    // x staging on owner lanes: s=u2 in [16,30) -> row0, [32,46) -> row1
    int fidx = -1, frr = 0;
    if ((l & 7) == 0) {
        if (u2 >= 16 && u2 < 16 + FF)      { fidx = u2 - 16; frr = 0; }
        else if (u2 >= 32 && u2 < 32 + FF) { fidx = u2 - 32; frr = 1; }
    }

    // ---- init zeros + x(0)/x(1) ----
    if (l < 96) { const int rr = (l >= 48); s2cat[0][rr][l - 48 * rr] = 0u; }
    if (l >= 96 && l < 130) {
        const int Li = l - 96; const int rr = (Li >= 17);
        s1cat[0][rr][7 + Li - 17 * rr] = 0u;
    }
    if (l == 192) s1cat[1][0][7] = 0u;
    if (l == 193) s1cat[1][1][7] = 0u;
    if (fidx >= 0) {
        ((_Float16*)s1cat[0][frr])[fidx] =
            (_Float16)x[((size_t)0 * BB + row0 + frr) * FF + fidx];
        xreg = x[((size_t)1 * BB + row0 + frr) * FF + fidx];
    }
    __syncthreads();

    // ---- pipelined time loop: ONE barrier per iteration ----
    for (int i = 0; i <= TT; ++i) {
        const int rp = (i - 1) & 1;
        const int cp = i & 1;
        const int np = cp ^ 1;

        // ===== layer-2 gates + h2 update for step i-1 (all lanes, 2 rows) =====
        if (i > 0) {
            #pragma unroll
            for (int rr = 0; rr < 2; ++rr) {
                const uint4* sv = ((const uint4*)s2cat[rp][rr]) + hf2 * 6;
                float a0 = b2r, a1 = 0.f, a2 = 0.f, a3 = 0.f;
                #pragma unroll
                for (int k = 0; k < 6; ++k) {
                    uint4 u = sv[k];
                    a0 = fdot2_(w2[4 * k + 0], bc_(u.x), a0);
                    a1 = fdot2_(w2[4 * k + 1], bc_(u.y), a1);
                    a2 = fdot2_(w2[4 * k + 2], bc_(u.z), a2);
                    a3 = fdot2_(w2[4 * k + 3], bc_(u.w), a3);
                }
                float g = (a0 + a1) + (a2 + a3);
                g += dpp_mov<0xB1>(g);
                const float gg = dpp_mov<0x104>(g);
                const float og = dpp_mov<0x106>(g);
                if ((l & 7) == 0) {
                    const float cn = sigmoidf_(g) * tanhf_(gg);
                    ((_Float16*)s2cat[cp][rr])[32 + u2] =
                        (_Float16)(sigmoidf_(og) * tanhf_(cn));
                }
            }
        }

        // ===== layer-1 gates + h1/c1 update for step i (one slot per lane) =====
        if (i < TT) {
            const uint4* sv = ((const uint4*)s1cat[cp][rw1]) + hf1 * 3;
            const uint4* wv = (const uint4*)ws1[r1 * 2 + hf1];
            float a0 = b1r, a1 = 0.f, a2 = 0.f, a3 = 0.f;
            #pragma unroll
            for (int k = 0; k < 3; ++k) {
                uint4 u = sv[k];
                uint4 w = wv[k];
                a0 = fdot2_(bc_(w.x), bc_(u.x), a0);
                a1 = fdot2_(bc_(w.y), bc_(u.y), a1);
                a2 = fdot2_(bc_(w.z), bc_(u.z), a2);
                a3 = fdot2_(bc_(w.w), bc_(u.w), a3);
            }
            float g = (a0 + a1) + (a2 + a3);
            g += dpp_mov<0xB1>(g);
            const float fg = dpp_mov<0x102>(g);
            const float gg = dpp_mov<0x104>(g);
            const float og = dpp_mov<0x106>(g);
            if ((l & 7) == 0) {
                const float cn = sigmoidf_(fg) * c1r + sigmoidf_(g) * tanhf_(gg);
                c1r = cn;
                const _Float16 hh = (_Float16)(sigmoidf_(og) * tanhf_(cn));
                ((_Float16*)s1cat[np][rw1])[16 + u1] = hh;  // L1, step i+1
                ((_Float16*)s2cat[cp][rw1])[u1]      = hh;  // L2, step i
            }
            // ----- stage x(i+1), prefetch x(i+2) (28 owner lanes) -----
            if (fidx >= 0) {
                ((_Float16*)s1cat[np][frr])[fidx] = (_Float16)xreg;
                const int tn = (i + 2 < TT) ? (i + 2) : (TT - 1);
                xreg = x[((size_t)tn * BB + row0 + frr) * FF + fidx];
            }
        }
        __syncthreads();
    }

    // ---- MLP head, both rows (h2(TT-1) f16 in s2cat[0][rr][32..95]) ----
    if (l < 16) {
        const int rr = l >> 3, j = l & 7;
        const _Float16* h2p = (const _Float16*)s2cat[0][rr];
        float a = bfc1[j];
        #pragma unroll
        for (int k = 0; k < H2; ++k)
            a = fmaf(fmaxf((float)h2p[32 + k], 0.0f), Wfc1[j * H2 + k], a);
        mlp1[rr][j] = fmaxf(a, 0.0f);
    }
    __syncthreads();
    if (l < 16) {
        const int rr = l >> 3, j = l & 7;
        float a = bfc2[j];
        #pragma unroll
        for (int k = 0; k < 8; ++k) a = fmaf(mlp1[rr][k], Wfc2[j * 8 + k], a);
        mlp2[rr][j] = fmaxf(a, 0.0f);
    }
    __syncthreads();
    if (l < 2) {
        float a = bfc[0];
        #pragma unroll
        for (int k = 0; k < 8; ++k) a = fmaf(mlp2[l][k], Wfc[k], a);
        out[row0 + l] = a;
    }
}

extern "C" void kernel_launch(void* const* d_in, const int* in_sizes, int n_in,
                              void* d_out, int out_size, void* d_ws, size_t ws_size,
                              hipStream_t stream) {
    const float* x    = (const float*)d_in[0];
    const float* Wih1 = (const float*)d_in[1];
    const float* Whh1 = (const float*)d_in[2];
    const float* bih1 = (const float*)d_in[3];
    const float* bhh1 = (const float*)d_in[4];
    const float* Wih2 = (const float*)d_in[5];
    const float* Whh2 = (const float*)d_in[6];
    const float* bih2 = (const float*)d_in[7];
    const float* bhh2 = (const float*)d_in[8];
    const float* Wfc1 = (const float*)d_in[9];
    const float* bfc1 = (const float*)d_in[10];
    const float* Wfc2 = (const float*)d_in[11];
    const float* bfc2 = (const float*)d_in[12];
    const float* Wfc  = (const float*)d_in[13];
    const float* bfc  = (const float*)d_in[14];
    float* out = (float*)d_out;

    lstm3_kernel<<<dim3(BB / 2), dim3(512), 0, stream>>>(
        x, Wih1, Whh1, bih1, bhh1, Wih2, Whh2, bih2, bhh2,
        Wfc1, bfc1, Wfc2, bfc2, Wfc, bfc, out);
}